// Round 1
// 156.099 us; speedup vs baseline: 1.0927x; 1.0927x over previous
//
#include <hip/hip_runtime.h>

#define NCELLS 1024
#define LDIM   30
#define GDIM   10000
#define NBATCH 64
#define GPB    256     // genes per block
#define CELLCAP 256    // >=10 sigma above binomial(1024,1/64) max; clamped

typedef unsigned int u32;

#define GLOBAL_AS __attribute__((address_space(1)))
#define LDS_AS    __attribute__((address_space(3)))

// grid = (NBATCH, ceil(G/GPB)), block = 256, one gene per thread.
// Latency-focused rewrite of the 71us version:
//  - classify: 64-iter serial scalar-load chain -> one vector load + ballot
//  - A staging: async global_load_lds (16B/lane) issued FIRST; the cell scan
//    and W-row loads run while it is in flight; single drain at the barrier
//  - cells[] 1024->256 entries: LDS 35.3KB -> 31.7KB -> 5 blocks/CU
//  - cell loop: id prefetch one pair ahead (breaks ds_read->s_load chain)
//  - out stores nontemporal (40MB streamed once; keep W/A in L2)
__global__ __launch_bounds__(256, 5) void decoder_kernel(
    const float* __restrict__ z,      // [N,L]     f32
    const void*  __restrict__ cand1,  // [N]  bcov or sf (classified on device)
    const void*  __restrict__ cand2,  // [N]  the other one
    const float* __restrict__ W,      // [L,G]     f32
    const float* __restrict__ A,      // [NB,G,L]  f32
    const float* __restrict__ Bb,     // [NB,G]    f32
    const float* __restrict__ px,     // [G]       f32
    float* __restrict__ out)          // [N*G + G] f32
{
    const int b   = blockIdx.x;
    const int tid = threadIdx.x;
    const int gb  = blockIdx.y * GPB;
    const int g   = gb + tid;
    const int gc  = g < GDIM ? g : GDIM - 1;   // clamp for pre-barrier loads

    __shared__ __align__(16) float a_sh[GPB * LDIM];  // 30 KB A-tile
    __shared__ int cells[CELLCAP];
    __shared__ int cnt;

    if (tid == 0) cnt = 0;
    __syncthreads();   // cheap: nothing in flight yet

    // ---- issue async A-tile staging first: global -> LDS, 16B per lane ----
    // LDS dest must be wave-uniform base + lane*16 (linear layout, no pad).
    const size_t abase = ((size_t)b * GDIM + gb) * LDIM;   // floats
    const size_t atot  = (size_t)NBATCH * GDIM * LDIM;
    {
        const int wbase = __builtin_amdgcn_readfirstlane(tid);  // 0/64/128/192
        #pragma unroll
        for (int k = 0; k < 8; k++) {
            const int i4 = k * 256 + tid;            // float4 index in tile
            if (i4 < GPB * LDIM / 4) {               // 1920 float4 total
                const size_t gidx = abase + (size_t)i4 * 4;
                if (gidx + 4 <= atot) {              // b=63 tail clamp (per-lane)
                    __builtin_amdgcn_global_load_lds(
                        (const GLOBAL_AS void*)(A + gidx),
                        (LDS_AS void*)(a_sh + (size_t)(k * 256 + wbase) * 4),
                        16, 0, 0);
                }
            }
        }
    }

    // ---- classify the two 1024-elem inputs (overlaps staging) ----
    // int32 0..63 words all < 64u; uniform-[0,1) f32 bit patterns are not.
    const u32 probe = ((const u32*)cand1)[tid & 63];
    const bool c1_is_int = __all(probe < 64u);
    const int*   bcov = c1_is_int ? (const int*)cand1   : (const int*)cand2;
    const float* sf   = c1_is_int ? (const float*)cand2 : (const float*)cand1;

    // ---- scan this batch's cells (overlaps staging) ----
    for (int i = tid; i < NCELLS; i += 256) {
        if (bcov[i] == b) {
            int p = atomicAdd(&cnt, 1);
            if (p < CELLCAP) cells[p] = i;   // never exceeded in practice
        }
    }

    // ---- W row + bias issued before the drain barrier ----
    float m[LDIM];
    #pragma unroll
    for (int l = 0; l < LDIM; l++) m[l] = W[(size_t)l * GDIM + gc];  // coalesced
    const float h3 = Bb[(size_t)b * GDIM + gc];

    __syncthreads();   // drains staging vmcnt + scan; LAST barrier in kernel

    if (g >= GDIM) return;   // safe: no __syncthreads below

    // fused matrix row in registers: m[l] = W[l,g] + a_sh[tid][l]
    // a_sh + tid*30 is 8B-aligned (120 B/row) -> ds_read_b64 pairs;
    // bank stride 30 mod 32 -> 2-way aliasing only (free on CDNA4)
    {
        const float2* ar = (const float2*)(a_sh + tid * LDIM);
        #pragma unroll
        for (int j = 0; j < LDIM / 2; j++) {
            float2 w = ar[j];
            m[2 * j]     += w.x;
            m[2 * j + 1] += w.y;
        }
    }

    // second output: inverse_dispersion = exp(px_r), f32 at offset N*G
    if (b == 0) out[(size_t)NCELLS * GDIM + g] = __expf(px[g]);

    const int total = cnt < CELLCAP ? cnt : CELLCAP;
    int id0 = cells[0];       // garbage-safe if total==0 (unused)
    int id1 = cells[1];
    int c = 0;
    for (; c + 2 <= total; c += 2) {     // 2 cells x 2 chains = 4 indep chains
        const int cell0 = __builtin_amdgcn_readfirstlane(id0);
        const int cell1 = __builtin_amdgcn_readfirstlane(id1);
        const int n0 = (c + 2 < total) ? c + 2 : 0;   // prefetch next pair
        const int n1 = (c + 3 < total) ? c + 3 : 0;
        id0 = cells[n0];
        id1 = cells[n1];
        const float* z0 = z + (size_t)cell0 * LDIM;   // uniform -> s_load
        const float* z1 = z + (size_t)cell1 * LDIM;
        const float s0 = sf[cell0], s1 = sf[cell1];   // uniform -> s_load
        float a0 = h3, b0 = 0.f, a1 = h3, b1 = 0.f;
        #pragma unroll
        for (int l = 0; l < LDIM; l += 2) {
            a0 = fmaf(m[l],     z0[l],     a0);
            b0 = fmaf(m[l + 1], z0[l + 1], b0);
            a1 = fmaf(m[l],     z1[l],     a1);
            b1 = fmaf(m[l + 1], z1[l + 1], b1);
        }
        float x0 = a0 + b0, x1 = a1 + b1;
        // stable softplus: max(x,0) + log(1 + exp(-|x|))
        float p0 = fmaxf(x0, 0.f) + __logf(1.f + __expf(-fabsf(x0)));
        float p1 = fmaxf(x1, 0.f) + __logf(1.f + __expf(-fabsf(x1)));
        __builtin_nontemporal_store(p0 * s0, &out[(size_t)cell0 * GDIM + g]);
        __builtin_nontemporal_store(p1 * s1, &out[(size_t)cell1 * GDIM + g]);
    }
    if (c < total) {                      // odd tail
        const int cell0 = __builtin_amdgcn_readfirstlane(id0);
        const float* z0 = z + (size_t)cell0 * LDIM;
        const float s0 = sf[cell0];
        float a0 = h3, b0 = 0.f;
        #pragma unroll
        for (int l = 0; l < LDIM; l += 2) {
            a0 = fmaf(m[l],     z0[l],     a0);
            b0 = fmaf(m[l + 1], z0[l + 1], b0);
        }
        float x0 = a0 + b0;
        float p0 = fmaxf(x0, 0.f) + __logf(1.f + __expf(-fabsf(x0)));
        __builtin_nontemporal_store(p0 * s0, &out[(size_t)cell0 * GDIM + g]);
    }
}

extern "C" void kernel_launch(void* const* d_in, const int* in_sizes, int n_in,
                              void* d_out, int out_size, void* d_ws, size_t ws_size,
                              hipStream_t stream) {
    // Bind inputs by element count (robust to ordering); the two 1024-element
    // inputs (bcov / size_factor) are disambiguated on device by content.
    const float* z  = nullptr;   // 30720
    const float* W  = nullptr;   // 300000
    const float* A  = nullptr;   // 19200000
    const float* Bb = nullptr;   // 640000
    const float* px = nullptr;   // 10000
    const void*  p1024[2] = {nullptr, nullptr};
    int n1024 = 0;
    for (int i = 0; i < n_in; i++) {
        switch (in_sizes[i]) {
            case NCELLS * LDIM:        z  = (const float*)d_in[i]; break;
            case LDIM * GDIM:          W  = (const float*)d_in[i]; break;
            case NBATCH * GDIM * LDIM: A  = (const float*)d_in[i]; break;
            case NBATCH * GDIM:        Bb = (const float*)d_in[i]; break;
            case GDIM:                 px = (const float*)d_in[i]; break;
            case NCELLS:
                if (n1024 < 2) p1024[n1024] = d_in[i];
                n1024++;
                break;
            default: break;
        }
    }
    if (!z || !W || !A || !Bb || !px || n1024 != 2) {  // fallback: dict order
        z  = (const float*)d_in[0];
        p1024[0] = d_in[1];
        p1024[1] = d_in[2];
        W  = (const float*)d_in[3];
        A  = (const float*)d_in[4];
        Bb = (const float*)d_in[5];
        px = (const float*)d_in[6];
    }
    float* out = (float*)d_out;

    decoder_kernel<<<dim3(NBATCH, (GDIM + GPB - 1) / GPB), 256, 0, stream>>>(
        z, p1024[0], p1024[1], W, A, Bb, px, out);
}